// Round 9
// baseline (239.015 us; speedup 1.0000x reference)
//
#include <hip/hip_runtime.h>
#include <hip/hip_fp16.h>

#define BB 16
#define HH 512
#define WW 512
#define NVV 35709
#define NTT 70000
#define HWW (HH * WW)
#define NVTOT (BB * NVV)          // 571344, divisible by 4

// World model (R0-R8, verified passing):
//   proj_geo, texture, nbl, ori_img : float32
//   is_visible, tri_inds, pixel_valid : int32
//   OUTPUT: float32, concatenated [render BHW3 | real BHW3]
//
// ws layout: VRec shw[NVTOT] (16 B/vertex: f32 x, f32 y, f16 rg, f16 b|vis)
//            __half2 acc[nb*HW*2] (8 B/pixel)
// R8 post-mortem: 3x gather cut in splat changed nothing -> either splat is
// small or it's latency-bound; compose at only 3.3 TB/s HBM (L3-resident
// reads). This round: 1-gather-per-vertex splat, fused prep, 8px compose
// with NT loads, compose split 4x for per-phase visibility in top-5.

typedef float fvec4 __attribute__((ext_vector_type(4)));
typedef int ivec4 __attribute__((ext_vector_type(4)));

struct VRec { float x, y; __half2 rg; __half2 bv; };   // 16 B

__device__ inline void pk_add(__half2* p, __half2 v)
{
    unsafeAtomicAdd(p, v);   // global_atomic_pk_add_f16 on gfx950
}

// ---------------------------------------------------------------------------
// prep: grid-stride. (a) zero acc region, (b) build 16B vertex records.
// Positions copied bit-exact f32; colors tex*nbl rounded to f16 (same as R8).
// ---------------------------------------------------------------------------
__global__ __launch_bounds__(256) void prep_kernel(
    const float4* __restrict__ proj4,
    const float4* __restrict__ tex4,
    const float4* __restrict__ nbl4,
    const int4* __restrict__ vis4,
    fvec4* __restrict__ shwv,
    float4* __restrict__ accz, long accN4)
{
    long tid = (long)blockIdx.x * blockDim.x + threadIdx.x;
    long stride = (long)gridDim.x * blockDim.x;

    float4 z = {0.f, 0.f, 0.f, 0.f};
    for (long i = tid; i < accN4; i += stride) accz[i] = z;

    for (long q = tid; q < NVTOT / 4; q += stride) {
        float4 P0 = proj4[q * 3 + 0], P1 = proj4[q * 3 + 1], P2 = proj4[q * 3 + 2];
        float4 T0 = tex4[q * 3 + 0], T1 = tex4[q * 3 + 1], T2 = tex4[q * 3 + 2];
        float4 N0 = nbl4[q * 3 + 0], N1 = nbl4[q * 3 + 1], N2 = nbl4[q * 3 + 2];
        int4 V = vis4[q];

        VRec r0, r1, r2, r3;
        r0.x = P0.x; r0.y = P0.y;
        r0.rg = __floats2half2_rn(T0.x * N0.x, T0.y * N0.y);
        r0.bv = __floats2half2_rn(T0.z * N0.z, V.x ? 1.f : 0.f);
        r1.x = P0.w; r1.y = P1.x;
        r1.rg = __floats2half2_rn(T0.w * N0.w, T1.x * N1.x);
        r1.bv = __floats2half2_rn(T1.y * N1.y, V.y ? 1.f : 0.f);
        r2.x = P1.z; r2.y = P1.w;
        r2.rg = __floats2half2_rn(T1.z * N1.z, T1.w * N1.w);
        r2.bv = __floats2half2_rn(T2.x * N2.x, V.z ? 1.f : 0.f);
        r3.x = P2.y; r3.y = P2.z;
        r3.rg = __floats2half2_rn(T2.y * N2.y, T2.z * N2.z);
        r3.bv = __floats2half2_rn(T2.w * N2.w, V.w ? 1.f : 0.f);

        shwv[q * 4 + 0] = __builtin_bit_cast(fvec4, r0);
        shwv[q * 4 + 1] = __builtin_bit_cast(fvec4, r1);
        shwv[q * 4 + 2] = __builtin_bit_cast(fvec4, r2);
        shwv[q * 4 + 3] = __builtin_bit_cast(fvec4, r3);
    }
}

// ---------------------------------------------------------------------------
// splat: 4 triangles/thread. 3 int4 index loads + 12 x 16B record gathers
// (all issued up front for MLP), then per-tri vis gate + centroid + 2 atomics.
// ---------------------------------------------------------------------------
__global__ __launch_bounds__(256) void splat_kernel(
    const fvec4* __restrict__ shwv,
    const int4* __restrict__ tri4,    // [NTT*3/4]
    __half2* __restrict__ acc,
    int b0)
{
    int g = blockIdx.x * blockDim.x + threadIdx.x;   // 4-triangle group
    if (g >= NTT / 4) return;                        // 17500 groups
    int bl = blockIdx.y;
    int base = (b0 + bl) * NVV;

    int4 wA = tri4[g * 3 + 0];
    int4 wB = tri4[g * 3 + 1];
    int4 wC = tri4[g * 3 + 2];
    int idx[12] = {wA.x, wA.y, wA.z, wA.w, wB.x, wB.y, wB.z, wB.w,
                   wC.x, wC.y, wC.z, wC.w};

    fvec4 vr[12];
#pragma unroll
    for (int k = 0; k < 12; ++k) vr[k] = shwv[base + idx[k]];

    long paccb = (long)bl * HWW;
#pragma unroll
    for (int k = 0; k < 4; ++k) {
        VRec s0 = __builtin_bit_cast(VRec, vr[k * 3 + 0]);
        VRec s1 = __builtin_bit_cast(VRec, vr[k * 3 + 1]);
        VRec s2 = __builtin_bit_cast(VRec, vr[k * 3 + 2]);

        // tri_w = min(vis): any invisible vertex kills the splat
        if (__high2float(s0.bv) == 0.f || __high2float(s1.bv) == 0.f ||
            __high2float(s2.bv) == 0.f) continue;

        float fx = ((s0.x + s1.x) + s2.x) / 3.0f;   // numpy f32 semantics
        float fy = ((s0.y + s1.y) + s2.y) / 3.0f;
        int px = (int)rintf(fx);                    // round-half-even
        int py = (int)rintf(fy);
        px = min(max(px, 0), WW - 1);
        py = min(max(py, 0), HH - 1);

        float cr = ((__low2float(s0.rg) + __low2float(s1.rg)) + __low2float(s2.rg)) / 3.0f;
        float cg = ((__high2float(s0.rg) + __high2float(s1.rg)) + __high2float(s2.rg)) / 3.0f;
        float cb = ((__low2float(s0.bv) + __low2float(s1.bv)) + __low2float(s2.bv)) / 3.0f;

        long lin = paccb + (long)py * WW + px;
        pk_add(&acc[lin * 2 + 0], __floats2half2_rn(cr, cg));
        pk_add(&acc[lin * 2 + 1], __floats2half2_rn(cb, 1.0f));
    }
}

// ---------------------------------------------------------------------------
// compose: 8 pixels/thread; NT loads for stream-once ori/pv; NT stores.
// Dispatched in `nchunks` equal chunks (per-phase profiling visibility).
// ---------------------------------------------------------------------------
__device__ inline float2 unpack_h2(float w)
{
    __half2 h = __builtin_bit_cast(__half2, w);
    return make_float2(__low2float(h), __high2float(h));
}

__global__ __launch_bounds__(256) void compose_kernel(
    const float4* __restrict__ accv,
    const fvec4* __restrict__ oriv,
    const ivec4* __restrict__ pvv,
    fvec4* __restrict__ outv,
    int b0, int nb, long l0, long lcount)
{
    long l = l0 + (long)blockIdx.x * blockDim.x + threadIdx.x;  // local 8px grp
    if (l >= l0 + lcount) return;
    long gg = (long)b0 * (HWW / 8) + l;                         // global group

    // acc: 4 x float4 = 8 pixels (2 px per float4)
    float4 A0 = accv[l * 4 + 0];
    float4 A1 = accv[l * 4 + 1];
    float4 A2 = accv[l * 4 + 2];
    float4 A3 = accv[l * 4 + 3];
    ivec4 PV0 = __builtin_nontemporal_load(&pvv[gg * 2 + 0]);
    ivec4 PV1 = __builtin_nontemporal_load(&pvv[gg * 2 + 1]);
    fvec4 O[6];
#pragma unroll
    for (int j = 0; j < 6; ++j)
        O[j] = __builtin_nontemporal_load(&oriv[gg * 6 + j]);

    float of[24];
#pragma unroll
    for (int j = 0; j < 6; ++j) {
        of[j * 4 + 0] = O[j].x; of[j * 4 + 1] = O[j].y;
        of[j * 4 + 2] = O[j].z; of[j * 4 + 3] = O[j].w;
    }
    float2 rg[8], bw[8];
    rg[0] = unpack_h2(A0.x); bw[0] = unpack_h2(A0.y);
    rg[1] = unpack_h2(A0.z); bw[1] = unpack_h2(A0.w);
    rg[2] = unpack_h2(A1.x); bw[2] = unpack_h2(A1.y);
    rg[3] = unpack_h2(A1.z); bw[3] = unpack_h2(A1.w);
    rg[4] = unpack_h2(A2.x); bw[4] = unpack_h2(A2.y);
    rg[5] = unpack_h2(A2.z); bw[5] = unpack_h2(A2.w);
    rg[6] = unpack_h2(A3.x); bw[6] = unpack_h2(A3.y);
    rg[7] = unpack_h2(A3.z); bw[7] = unpack_h2(A3.w);
    int pva[8] = {PV0.x, PV0.y, PV0.z, PV0.w, PV1.x, PV1.y, PV1.z, PV1.w};

    float rd[24], rl[24];
#pragma unroll
    for (int p = 0; p < 8; ++p) {
        float w = bw[p].y;
        bool pv = pva[p] > 0;
        bool cov = (w > 0.f) && pv;
        float dn = fmaxf(w, 1.f);
        rd[p * 3 + 0] = cov ? rg[p].x / dn : of[p * 3 + 0];
        rd[p * 3 + 1] = cov ? rg[p].y / dn : of[p * 3 + 1];
        rd[p * 3 + 2] = cov ? bw[p].x / dn : of[p * 3 + 2];
        rl[p * 3 + 0] = pv ? of[p * 3 + 0] : 0.f;
        rl[p * 3 + 1] = pv ? of[p * 3 + 1] : 0.f;
        rl[p * 3 + 2] = pv ? of[p * 3 + 2] : 0.f;
    }

    const long RO4 = (long)BB * HWW * 3 / 4;   // `real` offset in fvec4 units
#pragma unroll
    for (int j = 0; j < 6; ++j) {
        fvec4 R = {rd[j * 4 + 0], rd[j * 4 + 1], rd[j * 4 + 2], rd[j * 4 + 3]};
        fvec4 L = {rl[j * 4 + 0], rl[j * 4 + 1], rl[j * 4 + 2], rl[j * 4 + 3]};
        __builtin_nontemporal_store(R, &outv[gg * 6 + j]);
        __builtin_nontemporal_store(L, &outv[RO4 + gg * 6 + j]);
    }
}

extern "C" void kernel_launch(void* const* d_in, const int* in_sizes, int n_in,
                              void* d_out, int out_size, void* d_ws, size_t ws_size,
                              hipStream_t stream) {
    const float* proj = (const float*)d_in[0];
    const float* tex  = (const float*)d_in[1];
    const float* nbl  = (const float*)d_in[2];
    const float* ori  = (const float*)d_in[3];
    const int* vis    = (const int*)d_in[4];
    const int* tri    = (const int*)d_in[5];
    const int* pvalid = (const int*)d_in[6];
    float* out        = (float*)d_out;

    const size_t SHBYTES = (size_t)NVTOT * 16;         // 9.14 MB, 16B-aligned
    fvec4* shwv = (fvec4*)d_ws;
    char* accBase = (char*)d_ws + SHBYTES;

    const size_t perBatchBytes = (size_t)HWW * 8;      // 2 MiB / batch
    size_t remain = (ws_size > SHBYTES) ? ws_size - SHBYTES : 0;
    int nbMax = (int)(remain / perBatchBytes);
    if (nbMax < 1) nbMax = 1;
    if (nbMax > BB) nbMax = BB;

    for (int b0 = 0; b0 < BB; b0 += nbMax) {
        int nb = (BB - b0 < nbMax) ? (BB - b0) : nbMax;
        __half2* acc = (__half2*)accBase;

        long accN4 = (long)nb * HWW / 2;               // float4s to zero
        // prep covers zero + (on the first pass) the vertex records.
        // Records depend only on inputs; rebuild each pass is harmless but
        // wasteful -- only build on first pass.
        if (b0 == 0) {
            prep_kernel<<<2048, 256, 0, stream>>>(
                (const float4*)proj, (const float4*)tex, (const float4*)nbl,
                (const int4*)vis, shwv, (float4*)accBase, accN4);
        } else {
            prep_kernel<<<2048, 256, 0, stream>>>(
                (const float4*)proj, (const float4*)tex, (const float4*)nbl,
                (const int4*)vis, shwv, (float4*)accBase, accN4);
        }

        dim3 gs((NTT / 4 + 255) / 256, nb);
        splat_kernel<<<gs, 256, 0, stream>>>(shwv, (const int4*)tri, acc, b0);

        // compose in 4 chunks for profiling visibility
        long G = (long)nb * (HWW / 8);
        const int NCH = 4;
        long per = G / NCH;                            // nb*4096, exact
        for (int c = 0; c < NCH; ++c) {
            long l0 = (long)c * per;
            long lcount = (c == NCH - 1) ? (G - l0) : per;
            int blocks = (int)((lcount + 255) / 256);
            compose_kernel<<<blocks, 256, 0, stream>>>(
                (const float4*)accBase, (const fvec4*)ori, (const ivec4*)pvalid,
                (fvec4*)out, b0, nb, l0, lcount);
        }
    }
}

// Round 10
// 95.184 us; speedup vs baseline: 2.5111x; 2.5111x over previous
//
#include <hip/hip_runtime.h>
#include <hip/hip_fp16.h>

#define BB 16
#define HH 512
#define WW 512
#define NVV 35709
#define NTT 70000
#define HWW (HH * WW)
#define NVTOT (BB * NVV)          // 571344, divisible by 4

// World model (R0-R9, verified):
//   proj_geo, texture, nbl, ori_img : float32
//   is_visible, tri_inds, pixel_valid : int32
//   OUTPUT: float32, concatenated [render BHW3 | real BHW3]
//
// R9 post-mortem: prep+splat = ~7us total (VRec gather splat is cheap);
// compose regressed 4x from (a) 512-block chunks = 2 blocks/CU (11% occ)
// and (b) nontemporal LOADS (LRU-evict hint kills ori/pv caching).
// R10: keep R9 prep+splat; restore R7/R8 compose (4px/thread, 4096 blocks,
// cached loads, NT stores, single dispatch).
//
// ws layout: VRec shw[NVTOT] (16 B/vertex: f32 x, f32 y, f16 rg, f16 b|vis)
//            __half2 acc[nb*HW*2] (8 B/pixel: (r,g),(b,w))

typedef float fvec4 __attribute__((ext_vector_type(4)));

struct VRec { float x, y; __half2 rg; __half2 bv; };   // 16 B

__device__ inline void pk_add(__half2* p, __half2 v)
{
    unsafeAtomicAdd(p, v);   // global_atomic_pk_add_f16 on gfx950
}

// ---------------------------------------------------------------------------
// prep: grid-stride. (a) zero acc region, (b) build 16B vertex records.
// Positions copied bit-exact f32; colors tex*nbl rounded to f16.
// ---------------------------------------------------------------------------
__global__ __launch_bounds__(256) void prep_kernel(
    const float4* __restrict__ proj4,
    const float4* __restrict__ tex4,
    const float4* __restrict__ nbl4,
    const int4* __restrict__ vis4,
    fvec4* __restrict__ shwv,
    float4* __restrict__ accz, long accN4)
{
    long tid = (long)blockIdx.x * blockDim.x + threadIdx.x;
    long stride = (long)gridDim.x * blockDim.x;

    float4 z = {0.f, 0.f, 0.f, 0.f};
    for (long i = tid; i < accN4; i += stride) accz[i] = z;

    for (long q = tid; q < NVTOT / 4; q += stride) {
        float4 P0 = proj4[q * 3 + 0], P1 = proj4[q * 3 + 1], P2 = proj4[q * 3 + 2];
        float4 T0 = tex4[q * 3 + 0], T1 = tex4[q * 3 + 1], T2 = tex4[q * 3 + 2];
        float4 N0 = nbl4[q * 3 + 0], N1 = nbl4[q * 3 + 1], N2 = nbl4[q * 3 + 2];
        int4 V = vis4[q];

        VRec r0, r1, r2, r3;
        r0.x = P0.x; r0.y = P0.y;
        r0.rg = __floats2half2_rn(T0.x * N0.x, T0.y * N0.y);
        r0.bv = __floats2half2_rn(T0.z * N0.z, V.x ? 1.f : 0.f);
        r1.x = P0.w; r1.y = P1.x;
        r1.rg = __floats2half2_rn(T0.w * N0.w, T1.x * N1.x);
        r1.bv = __floats2half2_rn(T1.y * N1.y, V.y ? 1.f : 0.f);
        r2.x = P1.z; r2.y = P1.w;
        r2.rg = __floats2half2_rn(T1.z * N1.z, T1.w * N1.w);
        r2.bv = __floats2half2_rn(T2.x * N2.x, V.z ? 1.f : 0.f);
        r3.x = P2.y; r3.y = P2.z;
        r3.rg = __floats2half2_rn(T2.y * N2.y, T2.z * N2.z);
        r3.bv = __floats2half2_rn(T2.w * N2.w, V.w ? 1.f : 0.f);

        shwv[q * 4 + 0] = __builtin_bit_cast(fvec4, r0);
        shwv[q * 4 + 1] = __builtin_bit_cast(fvec4, r1);
        shwv[q * 4 + 2] = __builtin_bit_cast(fvec4, r2);
        shwv[q * 4 + 3] = __builtin_bit_cast(fvec4, r3);
    }
}

// ---------------------------------------------------------------------------
// splat: 4 triangles/thread. 3 int4 index loads + 12 x 16B record gathers
// (all issued up front for MLP), then per-tri vis gate + centroid + 2 atomics.
// ---------------------------------------------------------------------------
__global__ __launch_bounds__(256) void splat_kernel(
    const fvec4* __restrict__ shwv,
    const int4* __restrict__ tri4,    // [NTT*3/4]
    __half2* __restrict__ acc,
    int b0)
{
    int g = blockIdx.x * blockDim.x + threadIdx.x;   // 4-triangle group
    if (g >= NTT / 4) return;                        // 17500 groups
    int bl = blockIdx.y;
    int base = (b0 + bl) * NVV;

    int4 wA = tri4[g * 3 + 0];
    int4 wB = tri4[g * 3 + 1];
    int4 wC = tri4[g * 3 + 2];
    int idx[12] = {wA.x, wA.y, wA.z, wA.w, wB.x, wB.y, wB.z, wB.w,
                   wC.x, wC.y, wC.z, wC.w};

    fvec4 vr[12];
#pragma unroll
    for (int k = 0; k < 12; ++k) vr[k] = shwv[base + idx[k]];

    long paccb = (long)bl * HWW;
#pragma unroll
    for (int k = 0; k < 4; ++k) {
        VRec s0 = __builtin_bit_cast(VRec, vr[k * 3 + 0]);
        VRec s1 = __builtin_bit_cast(VRec, vr[k * 3 + 1]);
        VRec s2 = __builtin_bit_cast(VRec, vr[k * 3 + 2]);

        // tri_w = min(vis): any invisible vertex kills the splat
        if (__high2float(s0.bv) == 0.f || __high2float(s1.bv) == 0.f ||
            __high2float(s2.bv) == 0.f) continue;

        float fx = ((s0.x + s1.x) + s2.x) / 3.0f;   // numpy f32 semantics
        float fy = ((s0.y + s1.y) + s2.y) / 3.0f;
        int px = (int)rintf(fx);                    // round-half-even
        int py = (int)rintf(fy);
        px = min(max(px, 0), WW - 1);
        py = min(max(py, 0), HH - 1);

        float cr = ((__low2float(s0.rg) + __low2float(s1.rg)) + __low2float(s2.rg)) / 3.0f;
        float cg = ((__high2float(s0.rg) + __high2float(s1.rg)) + __high2float(s2.rg)) / 3.0f;
        float cb = ((__low2float(s0.bv) + __low2float(s1.bv)) + __low2float(s2.bv)) / 3.0f;

        long lin = paccb + (long)py * WW + px;
        pk_add(&acc[lin * 2 + 0], __floats2half2_rn(cr, cg));
        pk_add(&acc[lin * 2 + 1], __floats2half2_rn(cb, 1.0f));
    }
}

// ---------------------------------------------------------------------------
// compose: 4 pixels/thread (R7/R8 structure): cached loads, NT stores,
// single dispatch, 4096 blocks -> 16 blocks/CU.
// ---------------------------------------------------------------------------
__device__ inline float2 unpack_h2(float w)
{
    __half2 h = __builtin_bit_cast(__half2, w);
    return make_float2(__low2float(h), __high2float(h));
}

__global__ __launch_bounds__(256) void compose_kernel(
    const float4* __restrict__ accv,     // local (pass) accumulator as float4
    const float4* __restrict__ oriv,
    const int4* __restrict__ pvv,
    fvec4* __restrict__ outv,
    int b0, int nb)
{
    long q = (long)blockIdx.x * blockDim.x + threadIdx.x;   // local 4-pixel group
    long ngrp = (long)nb * (HWW / 4);
    if (q >= ngrp) return;
    long qg = (long)b0 * (HWW / 4) + q;                     // global group

    float4 A0 = accv[q * 2 + 0];   // pixels 0,1: (rg,bw),(rg,bw)
    float4 A1 = accv[q * 2 + 1];   // pixels 2,3
    int4 PV = pvv[qg];
    float4 O0 = oriv[qg * 3 + 0];
    float4 O1 = oriv[qg * 3 + 1];
    float4 O2 = oriv[qg * 3 + 2];

    float of[12] = {O0.x, O0.y, O0.z, O0.w, O1.x, O1.y, O1.z, O1.w,
                    O2.x, O2.y, O2.z, O2.w};
    float2 rg[4], bw[4];
    rg[0] = unpack_h2(A0.x); bw[0] = unpack_h2(A0.y);
    rg[1] = unpack_h2(A0.z); bw[1] = unpack_h2(A0.w);
    rg[2] = unpack_h2(A1.x); bw[2] = unpack_h2(A1.y);
    rg[3] = unpack_h2(A1.z); bw[3] = unpack_h2(A1.w);
    int pva[4] = {PV.x, PV.y, PV.z, PV.w};

    float rd[12], rl[12];
#pragma unroll
    for (int p = 0; p < 4; ++p) {
        float w = bw[p].y;
        bool pv = pva[p] > 0;
        bool cov = (w > 0.f) && pv;
        float dn = fmaxf(w, 1.f);
        rd[p * 3 + 0] = cov ? rg[p].x / dn : of[p * 3 + 0];
        rd[p * 3 + 1] = cov ? rg[p].y / dn : of[p * 3 + 1];
        rd[p * 3 + 2] = cov ? bw[p].x / dn : of[p * 3 + 2];
        rl[p * 3 + 0] = pv ? of[p * 3 + 0] : 0.f;
        rl[p * 3 + 1] = pv ? of[p * 3 + 1] : 0.f;
        rl[p * 3 + 2] = pv ? of[p * 3 + 2] : 0.f;
    }

    const long RO4 = (long)BB * HWW * 3 / 4;   // `real` offset in fvec4 units
    fvec4 R0 = {rd[0], rd[1], rd[2], rd[3]};
    fvec4 R1 = {rd[4], rd[5], rd[6], rd[7]};
    fvec4 R2 = {rd[8], rd[9], rd[10], rd[11]};
    fvec4 L0 = {rl[0], rl[1], rl[2], rl[3]};
    fvec4 L1 = {rl[4], rl[5], rl[6], rl[7]};
    fvec4 L2 = {rl[8], rl[9], rl[10], rl[11]};
    __builtin_nontemporal_store(R0, &outv[qg * 3 + 0]);
    __builtin_nontemporal_store(R1, &outv[qg * 3 + 1]);
    __builtin_nontemporal_store(R2, &outv[qg * 3 + 2]);
    __builtin_nontemporal_store(L0, &outv[RO4 + qg * 3 + 0]);
    __builtin_nontemporal_store(L1, &outv[RO4 + qg * 3 + 1]);
    __builtin_nontemporal_store(L2, &outv[RO4 + qg * 3 + 2]);
}

extern "C" void kernel_launch(void* const* d_in, const int* in_sizes, int n_in,
                              void* d_out, int out_size, void* d_ws, size_t ws_size,
                              hipStream_t stream) {
    const float* proj = (const float*)d_in[0];
    const float* tex  = (const float*)d_in[1];
    const float* nbl  = (const float*)d_in[2];
    const float* ori  = (const float*)d_in[3];
    const int* vis    = (const int*)d_in[4];
    const int* tri    = (const int*)d_in[5];
    const int* pvalid = (const int*)d_in[6];
    float* out        = (float*)d_out;

    const size_t SHBYTES = (size_t)NVTOT * 16;         // 9.14 MB, 16B-aligned
    fvec4* shwv = (fvec4*)d_ws;
    char* accBase = (char*)d_ws + SHBYTES;

    const size_t perBatchBytes = (size_t)HWW * 8;      // 2 MiB / batch
    size_t remain = (ws_size > SHBYTES) ? ws_size - SHBYTES : 0;
    int nbMax = (int)(remain / perBatchBytes);
    if (nbMax < 1) nbMax = 1;
    if (nbMax > BB) nbMax = BB;

    for (int b0 = 0; b0 < BB; b0 += nbMax) {
        int nb = (BB - b0 < nbMax) ? (BB - b0) : nbMax;
        __half2* acc = (__half2*)accBase;

        long accN4 = (long)nb * HWW / 2;               // float4s to zero
        prep_kernel<<<2048, 256, 0, stream>>>(
            (const float4*)proj, (const float4*)tex, (const float4*)nbl,
            (const int4*)vis, shwv, (float4*)accBase, accN4);

        dim3 gs((NTT / 4 + 255) / 256, nb);
        splat_kernel<<<gs, 256, 0, stream>>>(shwv, (const int4*)tri, acc, b0);

        long ngrp = (long)nb * (HWW / 4);
        compose_kernel<<<(int)((ngrp + 255) / 256), 256, 0, stream>>>(
            (const float4*)accBase, (const float4*)ori, (const int4*)pvalid,
            (fvec4*)out, b0, nb);
    }
}